// Round 14
// baseline (573.155 us; speedup 1.0000x reference)
//
#include <hip/hip_runtime.h>
#include <stdint.h>

typedef unsigned short u16;
typedef __attribute__((ext_vector_type(8))) short short8;
typedef __attribute__((ext_vector_type(4))) float f32x4;

#define DEVI __device__ __forceinline__

// problem constants
#define BB   256
#define LL   100
#define CC   55
#define DD   512
#define HH   8
#define DKK  64
#define MM   (BB * LL)   // 25600 tokens
#define KEMB 192         // 3 * 64 (c padded 55->64)
#define NSEG 17

DEVI float bf2f(u16 s) { union { unsigned int u; float f; } x; x.u = ((unsigned int)s) << 16; return x.f; }
DEVI u16 f2bf(float f) {
  union { float f; unsigned int u; } x; x.f = f;
  unsigned int u = x.u;
  return (u16)((u + 0x7FFFu + ((u >> 16) & 1u)) >> 16);
}

DEVI void async_lds16(const u16* gp, u16* lp) {
  __builtin_amdgcn_global_load_lds((const __attribute__((address_space(1))) void*)gp,
                                   (__attribute__((address_space(3))) void*)lp, 16, 0, 0);
}

DEVI void wave_lds_fence() {   // wave-local LDS RAW/WAR fence (no cross-wave sync)
  asm volatile("s_waitcnt lgkmcnt(0)" ::: "memory");
  __builtin_amdgcn_wave_barrier();
}

// bank-conflict XOR swizzle: chunk c of row r lives at slot c ^ sw(r),
// sw(r) = (r&3) ^ ((r>>2)&3). Self-inverse; sw(16a+l) == sw(l) so fragment
// reads can use sw(l15) when row bases are multiples of 16.
DEVI int swz_row(int r) { return (r & 3) ^ ((r >> 2) & 3); }

// ---------------- dtype detect + canonicalize ----------------
__global__ void detect_dtype(const u16* __restrict__ x, int* __restrict__ flag) {
  __shared__ int cnt[256];
  int tid = threadIdx.x;
  u16 u = x[2 * tid];
  int e = (u >> 7) & 0xFF;
  cnt[tid] = (e >= 0x5F && e <= 0x90) ? 1 : 0;   // |v| in [2^-32, 2^17]
  __syncthreads();
  for (int s = 128; s > 0; s >>= 1) { if (tid < s) cnt[tid] += cnt[tid + s]; __syncthreads(); }
  if (tid == 0) *flag = (cnt[0] >= 160) ? 0 : 1;
}

struct Segs { const void* src[NSEG]; int off[NSEG + 1]; };

__global__ void convert_all(Segs s, const int* __restrict__ flag, u16* __restrict__ dst) {
  int i = blockIdx.x * 256 + threadIdx.x;
  if (i >= s.off[NSEG]) return;
  int sidx = 0;
#pragma unroll
  for (int k = 1; k < NSEG; k++) if (i >= s.off[k]) sidx = k;
  int j = i - s.off[sidx];
  u16 v;
  if (*flag) v = f2bf(((const float*)s.src[sidx])[j]);
  else       v = ((const u16*)s.src[sidx])[j];
  dst[i] = v;
}

// ---------------- repack kernels (embedding conv -> GEMM) ----------------
__global__ void repack_w(const u16* __restrict__ tokw, u16* __restrict__ Wg) {
  int idx = blockIdx.x * 256 + threadIdx.x;   // 512*192
  if (idx >= 512 * KEMB) return;
  int d = idx / KEMB, j = idx % KEMB, k = j >> 6, c = j & 63;
  Wg[idx] = (c < CC) ? tokw[d * (CC * 3) + c * 3 + k] : (u16)0;
}

__global__ void repack_x(const u16* __restrict__ x, u16* __restrict__ Xg) {
  int idx = blockIdx.x * 256 + threadIdx.x;   // 25600*192
  if (idx >= MM * KEMB) return;
  int m = idx / KEMB, j = idx % KEMB, k = j >> 6, c = j & 63;
  int b = m / LL, l = m % LL;
  int l2 = l + k - 1; l2 = (l2 + LL) % LL;    // circular pad
  Xg[idx] = (c < CC) ? x[(size_t)(b * LL + l2) * CC + c] : (u16)0;
}

// ---------------- bf16 MFMA GEMM: out = A[M,K] @ W[N,K]^T (+epilogue) ----------------
// R0 2-phase structure: used for emb (short K under-amortizes the counted-vmcnt
// prologue -- R13 measured null) and proj (N=55 direct-store tail).
struct GemmW { const u16* W[3]; const u16* bias[3]; void* out[3]; };

template<int BM, int BN, int NTT, int TAG, bool QKV, bool DIRECT>
__global__ __launch_bounds__(256)
void gemm_bt(const u16* __restrict__ A, int K, GemmW w,
             const u16* __restrict__ pe,
             const u16* __restrict__ resid,
             int dogelu,
             int ldo, int nvalid,
             const int* __restrict__ dtf)    // DIRECT only: *dtf==1 -> fp32 store
{
  constexpr int BK = 32;
  constexpr int MI = BM / 32;
  constexpr int CW = BN / 2, NT = CW / 16;
  constexpr int SW = CW + 4;
  constexpr int STAGE_U16 = (BM + BN) * BK * 2;
  __shared__ alignas(16) u16 smem[STAGE_U16];
  u16* As = smem;
  u16* Bs = smem + BM * BK * 2;

  const int tid = threadIdx.x;
  const int lane = tid & 63;
  const int wv = __builtin_amdgcn_readfirstlane(tid >> 6);
  const int wm = wv & 1, wn = wv >> 1;
  const int l15 = lane & 15, qd = lane >> 4;
  const int swz = swz_row(l15);

  const int id = blockIdx.x;
  const int mpx = gridDim.x / (NTT * 8);
  const int xcd = id & 7, slot = id >> 3;
  const int m_t = xcd * mpx + slot / NTT;
  const int n_t = slot % NTT;
  const int m0 = m_t * BM;
  int n0 = n_t * BN;
  int sel = 0, n0l = n0;
  if (QKV) { sel = n0 >> 9; n0l = n0 & 511; }
  const u16* W = w.W[sel];
  const u16* bias = w.bias[sel];
  void* outp = w.out[sel];

  const f32x4 zf = {0.f, 0.f, 0.f, 0.f};
  f32x4 acc[MI][NT];
#pragma unroll
  for (int i = 0; i < MI; i++)
#pragma unroll
    for (int j = 0; j < NT; j++) acc[i][j] = zf;

  for (int k0 = 0; k0 < K; k0 += 2 * BK) {
    __syncthreads();
#pragma unroll
    for (int p = 0; p < 2; p++) {
      u16* Asp = As + p * BM * BK;
      u16* Bsp = Bs + p * BN * BK;
      const int kp = k0 + p * BK;
#pragma unroll
      for (int i = 0; i < BM / 64; i++) {
        int base = i * 256 + wv * 64;
        int idx = base + lane;
        int row = idx >> 2;
        int cs = ((idx & 3) ^ swz_row(row)) * 8;
        async_lds16(A + (size_t)(m0 + row) * K + kp + cs, Asp + base * 8);
      }
#pragma unroll
      for (int i = 0; i < BN / 64; i++) {
        int base = i * 256 + wv * 64;
        int idx = base + lane;
        int row = idx >> 2;
        int cs = ((idx & 3) ^ swz_row(row)) * 8;
        int gr = n0l + row; if (gr >= nvalid) gr = nvalid - 1;
        async_lds16(W + (size_t)gr * K + kp + cs, Bsp + base * 8);
      }
    }
    __syncthreads();

#pragma unroll
    for (int p = 0; p < 2; p++) {
      const u16* Asp = As + p * BM * BK;
      const u16* Bsp = Bs + p * BN * BK;
      short8 af[MI], bfr[NT];
#pragma unroll
      for (int mi = 0; mi < MI; mi++)
        af[mi] = *(const short8*)&Asp[(wm * (BM / 2) + mi * 16 + l15) * BK + ((qd ^ swz) * 8)];
#pragma unroll
      for (int ni = 0; ni < NT; ni++)
        bfr[ni] = *(const short8*)&Bsp[(wn * CW + ni * 16 + l15) * BK + ((qd ^ swz) * 8)];
#pragma unroll
      for (int mi = 0; mi < MI; mi++)
#pragma unroll
        for (int ni = 0; ni < NT; ni++)
          acc[mi][ni] = __builtin_amdgcn_mfma_f32_16x16x32_bf16(af[mi], bfr[ni], acc[mi][ni], 0, 0, 0);
    }
  }

  // C/D layout: col=lane&15, row=(lane>>4)*4+reg [verified m89/m91]
  if (DIRECT) {
    const int sf = (dtf != nullptr) ? *dtf : 0;
#pragma unroll
    for (int mi = 0; mi < MI; mi++)
#pragma unroll
      for (int ni = 0; ni < NT; ni++) {
        int gcol = n0l + wn * CW + ni * 16 + l15;
        float bv = (bias && gcol < nvalid) ? bf2f(bias[gcol]) : 0.f;
#pragma unroll
        for (int r = 0; r < 4; r++) {
          int grow = m0 + wm * (BM / 2) + mi * 16 + qd * 4 + r;
          if (gcol < nvalid) {
            float v = acc[mi][ni][r] + bv;
            if (sf) ((float*)outp)[(size_t)grow * ldo + gcol] = v;
            else    ((u16*)outp)[(size_t)grow * ldo + gcol] = f2bf(v);
          }
        }
      }
    return;
  }

  __syncthreads();
  u16* slab = smem + wv * 16 * SW;
#pragma unroll
  for (int mi = 0; mi < MI; mi++) {
    const int lr = wm * (BM / 2) + mi * 16 + qd * 4;
    float v[NT][4];
    if (!QKV && resid) {
#pragma unroll
      for (int ni = 0; ni < NT; ni++) {
        int col = n0l + wn * CW + ni * 16 + l15;
#pragma unroll
        for (int r = 0; r < 4; r++)
          v[ni][r] = bf2f(resid[(size_t)(m0 + lr + r) * DD + col]);
      }
    } else {
#pragma unroll
      for (int ni = 0; ni < NT; ni++)
#pragma unroll
        for (int r = 0; r < 4; r++) v[ni][r] = 0.f;
    }
#pragma unroll
    for (int ni = 0; ni < NT; ni++) {
      const int lc = wn * CW + ni * 16 + l15;
      float bv = bias ? bf2f(bias[n0l + lc]) : 0.f;
#pragma unroll
      for (int r = 0; r < 4; r++) {
        float x = v[ni][r] + acc[mi][ni][r] + bv;
        if (!QKV && pe) x += bf2f(pe[((m0 + lr + r) % LL) * DD + n0l + lc]);
        if (!QKV && dogelu) x = 0.5f * x * (1.f + erff(x * 0.70710678118654752f));
        v[ni][r] = x;
      }
    }
#pragma unroll
    for (int ni = 0; ni < NT; ni++)
#pragma unroll
      for (int r = 0; r < 4; r++)
        slab[(qd * 4 + r) * SW + ni * 16 + l15] = f2bf(v[ni][r]);
    wave_lds_fence();
    if (BN == 128) {
      int r2 = lane >> 2, c2 = (lane & 3) * 16;
      int grow = m0 + wm * (BM / 2) + mi * 16 + r2;
      u16* op = (u16*)outp + (size_t)grow * ldo + n0l + wn * CW + c2;
      *(short8*)&op[0] = *(const short8*)&slab[r2 * SW + c2];
      *(short8*)&op[8] = *(const short8*)&slab[r2 * SW + c2 + 8];
    } else {
      if (lane < 32) {
        int r2 = lane >> 1, c2 = (lane & 1) * 16;
        int grow = m0 + wm * (BM / 2) + mi * 16 + r2;
        u16* op = (u16*)outp + (size_t)grow * ldo + n0l + wn * CW + c2;
        *(short8*)&op[0] = *(const short8*)&slab[r2 * SW + c2];
        *(short8*)&op[8] = *(const short8*)&slab[r2 * SW + c2 + 8];
      }
    }
    wave_lds_fence();
  }
}

// ---------------- QKV GEMM: counted-vmcnt 3-slot ring, 512 threads ----------------
// VERBATIM from the verified R8 build (52.6us, MfmaUtil 30, 2 blk/CU).
__global__ __launch_bounds__(512)
void gemm_qkv(const u16* __restrict__ A, GemmW w)
{
  constexpr int K = DD;              // 512
  constexpr int NBK = K >> 5;        // 16
  constexpr int SLOT = 12288;        // u16/slot: A 128*32 + B 256*32
  __shared__ alignas(16) u16 smem[3 * SLOT];   // 72 KB

  const int tid = threadIdx.x;
  const int lane = tid & 63;
  const int wv = __builtin_amdgcn_readfirstlane(tid >> 6);   // 0..7
  const int wm = wv & 1, wn = wv >> 1;                       // 2 x 4
  const int l15 = lane & 15, qd = lane >> 4;
  const int swk = ((qd ^ swz_row(l15)) & 3) * 8;

  const int id = blockIdx.x;
  const int mpx = gridDim.x / 48;    // 25 (grid 1200 = 8 xcd * 25 m * 6 n)
  const int xcd = id & 7, sl = id >> 3;
  const int m_t = xcd * mpx + sl / 6;
  const int n_t = sl % 6;
  const int m0 = m_t * 128;
  const int sel = n_t >> 1;
  const int n0l = (n_t & 1) * 256;
  const u16* W = w.W[sel];
  const u16* bias = w.bias[sel];
  u16* outp = (u16*)w.out[sel];

  // per-thread staging sources (3 x 16B per K-step: 1 A-chunk, 2 B-chunks)
  const int arow = tid >> 2;
  const u16* a_src = A + (size_t)(m0 + arow) * K + ((tid & 3) ^ swz_row(arow)) * 8;
  const int br0 = tid >> 2, br1 = 128 + (tid >> 2);
  const u16* b_src0 = W + (size_t)(n0l + br0) * K + ((tid & 3) ^ swz_row(br0)) * 8;
  const u16* b_src1 = W + (size_t)(n0l + br1) * K + ((tid & 3) ^ swz_row(br1)) * 8;
  const int a_dst  = wv * 512;            // uniform; HW adds lane*16B
  const int b_dst0 = 4096 + wv * 512;
  const int b_dst1 = 8192 + wv * 512;

  auto STAGE = [&](int t) {
    u16* sb = smem + (t % 3) * SLOT;
    const int kp = t << 5;
    async_lds16(a_src + kp,  sb + a_dst);
    async_lds16(b_src0 + kp, sb + b_dst0);
    async_lds16(b_src1 + kp, sb + b_dst1);
  };

  const f32x4 zf = {0.f, 0.f, 0.f, 0.f};
  f32x4 acc[4][4];
#pragma unroll
  for (int i = 0; i < 4; i++)
#pragma unroll
    for (int j = 0; j < 4; j++) acc[i][j] = zf;

  STAGE(0);
  STAGE(1);
  for (int s = 0; s < NBK; ++s) {
    if (s + 1 < NBK) {
      asm volatile("s_waitcnt vmcnt(3)" ::: "memory");   // stage(s) landed
    } else {
      asm volatile("s_waitcnt vmcnt(0)" ::: "memory");
    }
    __builtin_amdgcn_s_barrier();                        // raw: no drain
    asm volatile("" ::: "memory");
    if (s + 2 < NBK) STAGE(s + 2);                       // post-barrier: slot safe
    const u16* sb = smem + (s % 3) * SLOT;
    short8 af[4], bf[4];
#pragma unroll
    for (int mi = 0; mi < 4; mi++)
      af[mi] = *(const short8*)&sb[(wm * 64 + mi * 16 + l15) * 32 + swk];
#pragma unroll
    for (int ni = 0; ni < 4; ni++)
      bf[ni] = *(const short8*)&sb[4096 + (wn * 64 + ni * 16 + l15) * 32 + swk];
#pragma unroll
    for (int mi = 0; mi < 4; mi++)
#pragma unroll
      for (int ni = 0; ni < 4; ni++)
        acc[mi][ni] = __builtin_amdgcn_mfma_f32_16x16x32_bf16(af[mi], bf[ni], acc[mi][ni], 0, 0, 0);
    asm volatile("s_waitcnt lgkmcnt(0)" ::: "memory");   // my reads done pre-next-barrier
  }
  __syncthreads();   // all landed (vmcnt(0) at s=NBK-1); LDS reused as slab

  // epilogue: per-wave private 64x72 slab -> coalesced 16B stores
  u16* slab = smem + wv * 4608;   // 8 waves x 9 KB = 72 KB: exact fit
#pragma unroll
  for (int mi = 0; mi < 4; mi++)
#pragma unroll
    for (int ni = 0; ni < 4; ni++) {
      float bv = bf2f(bias[n0l + wn * 64 + ni * 16 + l15]);
#pragma unroll
      for (int r = 0; r < 4; r++)
        slab[(mi * 16 + qd * 4 + r) * 72 + ni * 16 + l15] = f2bf(acc[mi][ni][r] + bv);
    }
  wave_lds_fence();
  {
    const int srow = lane >> 3, chk = lane & 7;
#pragma unroll
    for (int j = 0; j < 8; j++) {
      int row = j * 8 + srow;
      int grow = m0 + wm * 64 + row;
      u16* op = outp + (size_t)grow * DD + n0l + wn * 64 + chk * 8;
      *(short8*)op = *(const short8*)&slab[row * 72 + chk * 8];
    }
  }
}

// ---------------- Wo GEMM: counted-vmcnt 3-slot ring, BN=128, grid 800 ----------------
// R23 (validated R12: total 599.8->568.1). LDS 48KB -> 3 blk/CU; grid 800 fills
// one full round of 768 slots. 2 loads/thread/stage -> vmcnt(2). Resid epilogue
// in-place safe (wave reads only its own disjoint output tile before storing).
__global__ __launch_bounds__(512)
void gemm_wo(const u16* __restrict__ A, const u16* __restrict__ W,
             const u16* __restrict__ bias, const u16* __restrict__ resid,
             u16* __restrict__ outp)
{
  constexpr int K = DD;              // 512
  constexpr int NBK = K >> 5;        // 16
  constexpr int SLOT = 8192;         // u16/slot: A 128*32 + B 128*32
  __shared__ alignas(16) u16 smem[3 * SLOT];   // 48 KB

  const int tid = threadIdx.x;
  const int lane = tid & 63;
  const int wv = __builtin_amdgcn_readfirstlane(tid >> 6);
  const int wm = wv & 1, wn = wv >> 1;         // 2M x 4N
  const int l15 = lane & 15, qd = lane >> 4;
  const int swk = ((qd ^ swz_row(l15)) & 3) * 8;

  const int id = blockIdx.x;
  const int mpx = gridDim.x >> 5;    // 25 (grid 800 = 8 xcd * 25 m * 4 n)
  const int xcd = id & 7, sl = id >> 3;
  const int m_t = xcd * mpx + (sl >> 2);
  const int m0 = m_t * 128;
  const int n0l = (sl & 3) * 128;

  const int prow = tid >> 2;         // 0..127
  const int pcs = ((tid & 3) ^ swz_row(prow)) * 8;
  const u16* a_src = A + (size_t)(m0 + prow) * K + pcs;
  const u16* b_src = W + (size_t)(n0l + prow) * K + pcs;
  const int a_dst = wv * 512;
  const int b_dst = 4096 + wv * 512;

  auto STAGE = [&](int t) {
    u16* sb = smem + (t % 3) * SLOT;
    const int kp = t << 5;
    async_lds16(a_src + kp, sb + a_dst);
    async_lds16(b_src + kp, sb + b_dst);
  };

  const f32x4 zf = {0.f, 0.f, 0.f, 0.f};
  f32x4 acc[4][2];
#pragma unroll
  for (int i = 0; i < 4; i++)
#pragma unroll
    for (int j = 0; j < 2; j++) acc[i][j] = zf;

  STAGE(0);
  STAGE(1);
  for (int s = 0; s < NBK; ++s) {
    if (s + 1 < NBK) {
      asm volatile("s_waitcnt vmcnt(2)" ::: "memory");   // stage(s) landed
    } else {
      asm volatile("s_waitcnt vmcnt(0)" ::: "memory");
    }
    __builtin_amdgcn_s_barrier();                        // raw: no drain
    asm volatile("" ::: "memory");
    if (s + 2 < NBK) STAGE(s + 2);                       // post-barrier: slot safe
    const u16* sb = smem + (s % 3) * SLOT;
    short8 af[4], bf[2];
#pragma unroll
    for (int mi = 0; mi < 4; mi++)
      af[mi] = *(const short8*)&sb[(wm * 64 + mi * 16 + l15) * 32 + swk];
#pragma unroll
    for (int ni = 0; ni < 2; ni++)
      bf[ni] = *(const short8*)&sb[4096 + (wn * 32 + ni * 16 + l15) * 32 + swk];
#pragma unroll
    for (int mi = 0; mi < 4; mi++)
#pragma unroll
      for (int ni = 0; ni < 2; ni++)
        acc[mi][ni] = __builtin_amdgcn_mfma_f32_16x16x32_bf16(af[mi], bf[ni], acc[mi][ni], 0, 0, 0);
    asm volatile("s_waitcnt lgkmcnt(0)" ::: "memory");   // my reads done pre-next-barrier
  }
  __syncthreads();   // all landed; LDS reused as slab

  // epilogue: per-wave private 64x36 slab -> coalesced 16B stores
  u16* slab = smem + wv * 2304;   // 8 waves x 4.5 KB = 36 KB <= 48 KB
#pragma unroll
  for (int mi = 0; mi < 4; mi++)
#pragma unroll
    for (int ni = 0; ni < 2; ni++) {
      const int col = n0l + wn * 32 + ni * 16 + l15;
      float bv = bf2f(bias[col]);
#pragma unroll
      for (int r = 0; r < 4; r++) {
        const int grow = m0 + wm * 64 + mi * 16 + qd * 4 + r;
        float x = acc[mi][ni][r] + bv + bf2f(resid[(size_t)grow * DD + col]);
        slab[(mi * 16 + qd * 4 + r) * 36 + ni * 16 + l15] = f2bf(x);
      }
    }
  wave_lds_fence();
  {
    const int srow = lane >> 2, chk = lane & 3;   // 16 rows x 4 chunks per pass
#pragma unroll
    for (int j = 0; j < 4; j++) {
      int row = j * 16 + srow;
      int grow = m0 + wm * 64 + row;
      u16* op = outp + (size_t)grow * DD + n0l + wn * 32 + chk * 8;
      *(short8*)op = *(const short8*)&slab[row * 36 + chk * 8];
    }
  }
}

// ---------------- fused FFN: hout = h + gelu(h@W1^T + b1) @ W2^T + b2 ----------------
// R17: N-split phase 2 (grid 800); hout != h (ping-pong) so paired blocks never race.
__global__ __launch_bounds__(256)
void ffn_fused(const u16* __restrict__ h, const u16* __restrict__ W1,
               const u16* __restrict__ b1, const u16* __restrict__ W2,
               const u16* __restrict__ b2, u16* __restrict__ hout)
{
  constexpr int BM = 64, BK = 32, SW = 36;
  __shared__ alignas(16) u16 smem[4096 + 10496];
  u16* y      = smem;                        // [2][64][32] panels (A-format, swizzled)
  u16* shared = smem + 4096;
  u16* As  = shared;
  u16* Bs  = shared + 4096;
  u16* Bs2 = shared;
  u16* slabs = shared + 8192;

  const int tid = threadIdx.x;
  const int lane = tid & 63;
  const int wv = __builtin_amdgcn_readfirstlane(tid >> 6);
  const int wm = wv & 1, wn = wv >> 1;
  const int l15 = lane & 15, qd = lane >> 4;
  const int swz = swz_row(l15);
  const int id = blockIdx.x;
  const int mpx = gridDim.x >> 3;            // 100
  const int lid = (id & 7) * mpx + (id >> 3);  // XCD-contiguous 0..799
  const int m0 = (lid >> 1) * BM;
  const int nh = lid & 1;                    // phase-2 N-half

  const int srow = tid >> 2;
  const int scs = ((tid & 3) ^ swz_row(srow)) * 8;   // swizzled staging chunk
  const f32x4 zf = {0.f, 0.f, 0.f, 0.f};

  // ---- phase 1: y = gelu(h @ W1^T + b1) ----
  f32x4 acc[2][2];
#pragma unroll
  for (int i = 0; i < 2; i++)
#pragma unroll
    for (int j = 0; j < 2; j++) acc[i][j] = zf;

  for (int k0 = 0; k0 < DD; k0 += 64) {
    __syncthreads();
#pragma unroll
    for (int p = 0; p < 2; p++) {
      const int kp = k0 + p * BK;
      async_lds16(h  + (size_t)(m0 + srow) * DD + kp + scs, As + p * 2048 + tid * 8);
      async_lds16(W1 + (size_t)srow * DD + kp + scs,        Bs + p * 2048 + tid * 8);
    }
    __syncthreads();
#pragma unroll
    for (int p = 0; p < 2; p++) {
      short8 af[2], bfr[2];
#pragma unroll
      for (int mi = 0; mi < 2; mi++)
        af[mi] = *(const short8*)&As[p * 2048 + (wm * 32 + mi * 16 + l15) * BK + ((qd ^ swz) * 8)];
#pragma unroll
      for (int ni = 0; ni < 2; ni++)
        bfr[ni] = *(const short8*)&Bs[p * 2048 + (wn * 32 + ni * 16 + l15) * BK + ((qd ^ swz) * 8)];
#pragma unroll
      for (int mi = 0; mi < 2; mi++)
#pragma unroll
        for (int ni = 0; ni < 2; ni++)
          acc[mi][ni] = __builtin_amdgcn_mfma_f32_16x16x32_bf16(af[mi], bfr[ni], acc[mi][ni], 0, 0, 0);
    }
  }
  // y park (swizzled): element (row, kpos) -> slot (kpos>>3) ^ sw(row)
#pragma unroll
  for (int mi = 0; mi < 2; mi++)
#pragma unroll
    for (int ni = 0; ni < 2; ni++) {
      float bv = bf2f(b1[wn * 32 + ni * 16 + l15]);
#pragma unroll
      for (int r = 0; r < 4; r++) {
        int row = wm * 32 + mi * 16 + qd * 4 + r;
        int kpos = ni * 16 + l15;
        int slot = ((kpos >> 3) ^ swz_row(row)) & 3;
        float x = acc[mi][ni][r] + bv;
        x = 0.5f * x * (1.f + erff(x * 0.70710678118654752f));
        y[wn * 2048 + row * BK + slot * 8 + (kpos & 7)] = f2bf(x);
      }
    }
  __syncthreads();

  // ---- phase 2: hout = h + y @ W2^T + b2, 4 chunks of 64 cols (this half) ----
  auto stage2 = [&](int buf, int nc) {
#pragma unroll
    for (int p = 0; p < 2; p++)
      async_lds16(W2 + (size_t)(nc * 64 + srow) * 64 + p * BK + scs,
                  Bs2 + buf * 4096 + p * 2048 + tid * 8);
  };
  const int nc0 = nh * 4, nc1 = nc0 + 4;
  stage2(0, nc0);
  int cur = 0;
  u16* slab = slabs + wv * 16 * SW;
  for (int nc = nc0; nc < nc1; nc++) {
    __syncthreads();
    if (nc + 1 < nc1) stage2(cur ^ 1, nc + 1);
    f32x4 a2[2][2];
#pragma unroll
    for (int i = 0; i < 2; i++)
#pragma unroll
      for (int j = 0; j < 2; j++) a2[i][j] = zf;
#pragma unroll
    for (int p = 0; p < 2; p++) {
      short8 af[2], bfr[2];
#pragma unroll
      for (int mi = 0; mi < 2; mi++)
        af[mi] = *(const short8*)&y[p * 2048 + (wm * 32 + mi * 16 + l15) * BK + ((qd ^ swz) * 8)];
#pragma unroll
      for (int ni = 0; ni < 2; ni++)
        bfr[ni] = *(const short8*)&Bs2[cur * 4096 + p * 2048 + (wn * 32 + ni * 16 + l15) * BK + ((qd ^ swz) * 8)];
#pragma unroll
      for (int mi = 0; mi < 2; mi++)
#pragma unroll
        for (int ni = 0; ni < 2; ni++)
          a2[mi][ni] = __builtin_amdgcn_mfma_f32_16x16x32_bf16(af[mi], bfr[ni], a2[mi][ni], 0, 0, 0);
    }
    const int n0l = nc * 64;
#pragma unroll
    for (int mi = 0; mi < 2; mi++) {
      const int lr = wm * 32 + mi * 16 + qd * 4;
      float v[2][4];
#pragma unroll
      for (int ni = 0; ni < 2; ni++) {
        int col = n0l + wn * 32 + ni * 16 + l15;
        float bv = bf2f(b2[col]);
#pragma unroll
        for (int r = 0; r < 4; r++)
          v[ni][r] = bf2f(h[(size_t)(m0 + lr + r) * DD + col]) + a2[mi][ni][r] + bv;
      }
#pragma unroll
      for (int ni = 0; ni < 2; ni++)
#pragma unroll
        for (int r = 0; r < 4; r++)
          slab[(qd * 4 + r) * SW + ni * 16 + l15] = f2bf(v[ni][r]);
      wave_lds_fence();
      if (lane < 32) {
        int r2 = lane >> 1, c2 = (lane & 1) * 16;
        int grow = m0 + wm * 32 + mi * 16 + r2;
        u16* op = hout + (size_t)grow * DD + n0l + wn * 32 + c2;
        *(short8*)&op[0] = *(const short8*)&slab[r2 * SW + c2];
        *(short8*)&op[8] = *(const short8*)&slab[r2 * SW + c2 + 8];
      }
      wave_lds_fence();
    }
    cur ^= 1;
  }
}

// ---------------- fused attention: one block per (b,h) ----------------
// R17: LDS 32 KB (P parked in dead Ks region, PV in two 64-col passes).
__global__ __launch_bounds__(256)
void attn(const u16* __restrict__ qg, const u16* __restrict__ kg,
          const u16* __restrict__ vg, u16* __restrict__ og)
{
  constexpr int LP = 128;
  __shared__ alignas(16) u16 Ks[LP * DKK];   // 16 KB; post-QK^T: P-chunk, then Os
  __shared__ alignas(16) u16 Vt[DKK * LP];   // 16 KB

  const int bh = blockIdx.x;
  const int b = bh >> 3, h = bh & 7;
  const size_t base = (size_t)b * LL * DD + (size_t)h * DKK;
  const int tid = threadIdx.x, lane = tid & 63, wv = tid >> 6;
  const int l15 = lane & 15, qd = lane >> 4;
  const short8 z8 = {0, 0, 0, 0, 0, 0, 0, 0};

  for (int i = tid; i < LP * 8; i += 256) {
    int row = i >> 3, e8 = (i & 7) * 8;
    short8 val = z8;
    if (row < LL) val = *(const short8*)(kg + base + (size_t)row * DD + e8);
    *(short8*)&Ks[row * DKK + e8] = val;
  }
  for (int i = tid; i < LP * 8; i += 256) {
    int j = i & 127, d0 = (i >> 7) * 8;
    short8 val = z8;
    if (j < LL) val = *(const short8*)(vg + base + (size_t)j * DD + d0);
#pragma unroll
    for (int u = 0; u < 8; u++) Vt[(d0 + u) * LP + j] = (u16)val[u];
  }
  __syncthreads();

  const f32x4 zf = {0.f, 0.f, 0.f, 0.f};
  f32x4 sc[2][8];
#pragma unroll
  for (int it = 0; it < 2; it++)
#pragma unroll
    for (int jt = 0; jt < 8; jt++) sc[it][jt] = zf;

  short8 af[2][2];
#pragma unroll
  for (int it = 0; it < 2; it++) {
    int row = (2 * wv + it) * 16 + l15;
#pragma unroll
    for (int ks = 0; ks < 2; ks++) {
      short8 val = z8;
      if (row < LL) val = *(const short8*)(qg + base + (size_t)row * DD + ks * 32 + qd * 8);
      af[it][ks] = val;
    }
  }
#pragma unroll
  for (int jt = 0; jt < 8; jt++) {
    short8 b0 = *(const short8*)&Ks[(jt * 16 + l15) * DKK + qd * 8];
    short8 b1 = *(const short8*)&Ks[(jt * 16 + l15) * DKK + 32 + qd * 8];
#pragma unroll
    for (int it = 0; it < 2; it++) {
      sc[it][jt] = __builtin_amdgcn_mfma_f32_16x16x32_bf16(af[it][0], b0, sc[it][jt], 0, 0, 0);
      sc[it][jt] = __builtin_amdgcn_mfma_f32_16x16x32_bf16(af[it][1], b1, sc[it][jt], 0, 0, 0);
    }
  }

  // softmax fully in registers: sc := P (normalized probabilities)
  constexpr float scale = 0.125f;
#pragma unroll
  for (int it = 0; it < 2; it++) {
#pragma unroll
    for (int r = 0; r < 4; r++) {
      float vals[8];
      float mx = -1e30f;
#pragma unroll
      for (int jt = 0; jt < 8; jt++) {
        int col = jt * 16 + l15;
        float vv = sc[it][jt][r] * scale;
        if (col >= LL) vv = -1e30f;
        vals[jt] = vv;
        mx = fmaxf(mx, vv);
      }
#pragma unroll
      for (int off = 1; off < 16; off <<= 1) mx = fmaxf(mx, __shfl_xor(mx, off, 64));
      float s = 0.f;
#pragma unroll
      for (int jt = 0; jt < 8; jt++) { float p = __expf(vals[jt] - mx); vals[jt] = p; s += p; }
#pragma unroll
      for (int off = 1; off < 16; off <<= 1) s += __shfl_xor(s, off, 64);
      float inv = 1.f / s;
#pragma unroll
      for (int jt = 0; jt < 8; jt++) sc[it][jt][r] = vals[jt] * inv;
    }
  }
  __syncthreads();   // all waves' QK^T reads of Ks complete -> Ks reusable

  u16* Pc = Ks;      // P-chunk [128][64]
  f32x4 oc[2][4];
#pragma unroll
  for (int it = 0; it < 2; it++)
#pragma unroll
    for (int dt = 0; dt < 4; dt++) oc[it][dt] = zf;

  // ---- pass A: P cols 0..63 -> PV k-slices 0,1 ----
#pragma unroll
  for (int it = 0; it < 2; it++) {
    int rb = (2 * wv + it) * 16 + qd * 4;
#pragma unroll
    for (int r = 0; r < 4; r++)
#pragma unroll
      for (int jt = 0; jt < 4; jt++)
        Pc[(rb + r) * DKK + jt * 16 + l15] = f2bf(sc[it][jt][r]);
  }
  __syncthreads();
#pragma unroll
  for (int ks = 0; ks < 2; ks++) {
    short8 ap[2];
#pragma unroll
    for (int it = 0; it < 2; it++)
      ap[it] = *(const short8*)&Pc[((2 * wv + it) * 16 + l15) * DKK + ks * 32 + qd * 8];
#pragma unroll
    for (int dt = 0; dt < 4; dt++) {
      short8 bv = *(const short8*)&Vt[(dt * 16 + l15) * LP + ks * 32 + qd * 8];
#pragma unroll
      for (int it = 0; it < 2; it++)
        oc[it][dt] = __builtin_amdgcn_mfma_f32_16x16x32_bf16(ap[it], bv, oc[it][dt], 0, 0, 0);
    }
  }
  __syncthreads();

  // ---- pass B: P cols 64..127 -> PV k-slices 2,3 ----
#pragma unroll
  for (int it = 0; it < 2; it++) {
    int rb = (2 * wv + it) * 16 + qd * 4;
#pragma unroll
    for (int r = 0; r < 4; r++)
#pragma unroll
      for (int jt = 4; jt < 8; jt++)
        Pc[(rb + r) * DKK + (jt - 4) * 16 + l15] = f2bf(sc[it][jt][r]);
  }
  __syncthreads();
#pragma unroll
  for (int ks = 2; ks < 4; ks++) {
    short8 ap[2];
#pragma unroll
    for (int it = 0; it < 2; it++)
      ap[it] = *(const short8*)&Pc[((2 * wv + it) * 16 + l15) * DKK + (ks - 2) * 32 + qd * 8];
#pragma unroll
    for (int dt = 0; dt < 4; dt++) {
      short8 bv = *(const short8*)&Vt[(dt * 16 + l15) * LP + ks * 32 + qd * 8];
#pragma unroll
      for (int it = 0; it < 2; it++)
        oc[it][dt] = __builtin_amdgcn_mfma_f32_16x16x32_bf16(ap[it], bv, oc[it][dt], 0, 0, 0);
    }
  }

  __syncthreads();
  u16* Os = Ks;      // [128][64], Pc dead
#pragma unroll
  for (int it = 0; it < 2; it++) {
    int rb = (2 * wv + it) * 16 + qd * 4;
#pragma unroll
    for (int dt = 0; dt < 4; dt++)
#pragma unroll
      for (int r = 0; r < 4; r++)
        Os[(rb + r) * DKK + dt * 16 + l15] = f2bf(oc[it][dt][r]);
  }
  __syncthreads();
  {
    int row = tid >> 1, c0 = (tid & 1) * 32;
    if (row < LL) {
      u16* op = og + base + (size_t)row * DD + c0;
#pragma unroll
      for (int c = 0; c < 32; c += 8)
        *(short8*)&op[c] = *(const short8*)&Os[row * DKK + c0 + c];
    }
  }
}

// ---------------- launch ----------------
extern "C" void kernel_launch(void* const* d_in, const int* in_sizes, int n_in,
                              void* d_out, int out_size, void* d_ws, size_t ws_size,
                              hipStream_t stream)
{
  (void)in_sizes; (void)n_in; (void)out_size; (void)ws_size;

  char* ws = (char*)d_ws;
  size_t off = 0;
  auto alloc = [&](size_t bytes) { char* p = ws + off; off += (bytes + 255) & ~(size_t)255; return p; };
  int* dflag = (int*)alloc(256);
  static const int seg_sizes[NSEG] = {
    MM * CC, DD * CC * 3, LL * DD,
    3 * DD * DD, 3 * DD, 3 * DD * DD, 3 * DD, 3 * DD * DD, 3 * DD,
    3 * DD * DD, 3 * DD, 3 * 64 * DD, 3 * 64, 3 * DD * 64, 3 * DD,
    CC * DD, CC
  };
  static const int seg_input[NSEG] = {0, 1, 2, 3, 4, 5, 6, 7, 8, 11, 12, 13, 14, 15, 16, 17, 18};
  int total = 0, segoff[NSEG + 1];
  for (int i = 0; i < NSEG; i++) { segoff[i] = total; total += seg_sizes[i]; }
  segoff[NSEG] = total;
  u16* canon = (u16*)alloc((size_t)total * 2);

  u16* hbf = (u16*)alloc((size_t)MM * DD * 2);   // residual stream (ping)
  u16* h2  = (u16*)alloc((size_t)MM * DD * 2);   // residual stream (pong, FFN out)
  u16* qb  = (u16*)alloc((size_t)MM * DD * 2);
  u16* kb  = (u16*)alloc((size_t)MM * DD * 2);
  u16* vb  = (u16*)alloc((size_t)MM * DD * 2);
  u16* ob  = (u16*)alloc((size_t)MM * DD * 2);
  u16* Wg  = (u16*)alloc((size_t)512 * KEMB * 2);
  u16* Xg  = qb;   // alias: Xg dead before qb first written (stream-serialized)

  const u16* xc  = canon + segoff[0];
  const u16* twc = canon + segoff[1];
  const u16* pec = canon + segoff[2];
  const u16* Wqc = canon + segoff[3];  const u16* bqc = canon + segoff[4];
  const u16* Wkc = canon + segoff[5];  const u16* bkc = canon + segoff[6];
  const u16* Wvc = canon + segoff[7];  const u16* bvc = canon + segoff[8];
  const u16* Woc = canon + segoff[9];  const u16* boc = canon + segoff[10];
  const u16* W1c = canon + segoff[11]; const u16* b1c = canon + segoff[12];
  const u16* W2c = canon + segoff[13]; const u16* b2c = canon + segoff[14];
  const u16* pwc = canon + segoff[15]; const u16* pbc = canon + segoff[16];

  Segs sg;
  for (int i = 0; i < NSEG; i++) { sg.src[i] = d_in[seg_input[i]]; sg.off[i] = segoff[i]; }
  sg.off[NSEG] = total;

  dim3 blk(256);
  detect_dtype<<<dim3(1), blk, 0, stream>>>((const u16*)d_in[0], dflag);
  convert_all<<<dim3((total + 255) / 256), blk, 0, stream>>>(sg, dflag, canon);
  repack_w<<<dim3((512 * KEMB + 255) / 256), blk, 0, stream>>>(twc, Wg);
  repack_x<<<dim3((MM * KEMB + 255) / 256), blk, 0, stream>>>(xc, Xg);

  auto W1of = [&](const u16* p) { GemmW g{}; g.W[0] = g.W[1] = g.W[2] = p; return g; };

  // embedding GEMM: h = Xg @ Wg^T + pe -> hbf   [TAG 0]  grid 200*8, XCD-decoded
  { GemmW g = W1of(Wg); g.out[0] = hbf;
    gemm_bt<128, 64, 8, 0, false, false><<<dim3(1600), blk, 0, stream>>>(Xg, KEMB, g, pec, nullptr, 0, DD, DD, nullptr); }

  u16* hc = hbf;   // current residual stream
  for (int l = 0; l < 3; l++) {
    const u16* Wq_l = Wqc + (size_t)l * DD * DD; const u16* bq_l = bqc + l * DD;
    const u16* Wk_l = Wkc + (size_t)l * DD * DD; const u16* bk_l = bkc + l * DD;
    const u16* Wv_l = Wvc + (size_t)l * DD * DD; const u16* bv_l = bvc + l * DD;
    const u16* Wo_l = Woc + (size_t)l * DD * DD; const u16* bo_l = boc + l * DD;
    const u16* W1_l = W1c + (size_t)l * 64 * DD; const u16* b1_l = b1c + l * 64;
    const u16* W2_l = W2c + (size_t)l * DD * 64; const u16* b2_l = b2c + l * DD;

    // fused QKV: counted-vmcnt 3-slot pipeline, grid 8*25*6 = 1200, 512 threads
    { GemmW g{}; g.W[0] = Wq_l; g.W[1] = Wk_l; g.W[2] = Wv_l;
      g.bias[0] = bq_l; g.bias[1] = bk_l; g.bias[2] = bv_l;
      g.out[0] = qb; g.out[1] = kb; g.out[2] = vb;
      gemm_qkv<<<dim3(1200), dim3(512), 0, stream>>>(hc, g); }

    attn<<<dim3(BB * HH), blk, 0, stream>>>(qb, kb, vb, ob);

    // h = h + o @ Wo^T + bo  (counted-vmcnt BN=128 grid 800, resid epilogue, in-place)
    gemm_wo<<<dim3(800), dim3(512), 0, stream>>>(ob, Wo_l, bo_l, hc, hc);

    // fused FFN: hn = hc + gelu(hc@W1^T+b1)@W2^T + b2  (ping-pong, N-split grid 800)
    u16* hn = (hc == hbf) ? h2 : hbf;
    ffn_fused<<<dim3(800), blk, 0, stream>>>(hc, W1_l, b1_l, W2_l, b2_l, hn);
    hc = hn;
  }
  // out = h @ proj_w^T + proj_b (N=55, direct masked stores; dtype per flag)   [TAG 5]
  { GemmW g = W1of(pwc); g.bias[0] = pbc; g.out[0] = d_out;
    gemm_bt<64, 64, 1, 5, false, true><<<dim3(400), blk, 0, stream>>>(hc, DD, g, nullptr, nullptr, 0, CC, CC, dflag); }
}

// Round 15
// 567.005 us; speedup vs baseline: 1.0108x; 1.0108x over previous
//
#include <hip/hip_runtime.h>
#include <stdint.h>

typedef unsigned short u16;
typedef __attribute__((ext_vector_type(8))) short short8;
typedef __attribute__((ext_vector_type(4))) float f32x4;

#define DEVI __device__ __forceinline__

// problem constants
#define BB   256
#define LL   100
#define CC   55
#define DD   512
#define HH   8
#define DKK  64
#define MM   (BB * LL)   // 25600 tokens
#define KEMB 192         // 3 * 64 (c padded 55->64)
#define NSEG 17

DEVI float bf2f(u16 s) { union { unsigned int u; float f; } x; x.u = ((unsigned int)s) << 16; return x.f; }
DEVI u16 f2bf(float f) {
  union { float f; unsigned int u; } x; x.f = f;
  unsigned int u = x.u;
  return (u16)((u + 0x7FFFu + ((u >> 16) & 1u)) >> 16);
}

DEVI void async_lds16(const u16* gp, u16* lp) {
  __builtin_amdgcn_global_load_lds((const __attribute__((address_space(1))) void*)gp,
                                   (__attribute__((address_space(3))) void*)lp, 16, 0, 0);
}

DEVI void wave_lds_fence() {   // wave-local LDS RAW/WAR fence (no cross-wave sync)
  asm volatile("s_waitcnt lgkmcnt(0)" ::: "memory");
  __builtin_amdgcn_wave_barrier();
}

// bank-conflict XOR swizzle: chunk c of row r lives at slot c ^ sw(r),
// sw(r) = (r&3) ^ ((r>>2)&3). Self-inverse; sw(16a+l) == sw(l) so fragment
// reads can use sw(l15) when row bases are multiples of 16.
DEVI int swz_row(int r) { return (r & 3) ^ ((r >> 2) & 3); }

// ---------------- dtype detect + canonicalize ----------------
__global__ void detect_dtype(const u16* __restrict__ x, int* __restrict__ flag) {
  __shared__ int cnt[256];
  int tid = threadIdx.x;
  u16 u = x[2 * tid];
  int e = (u >> 7) & 0xFF;
  cnt[tid] = (e >= 0x5F && e <= 0x90) ? 1 : 0;   // |v| in [2^-32, 2^17]
  __syncthreads();
  for (int s = 128; s > 0; s >>= 1) { if (tid < s) cnt[tid] += cnt[tid + s]; __syncthreads(); }
  if (tid == 0) *flag = (cnt[0] >= 160) ? 0 : 1;
}

struct Segs { const void* src[NSEG]; int off[NSEG + 1]; };

__global__ void convert_all(Segs s, const int* __restrict__ flag, u16* __restrict__ dst) {
  int i = blockIdx.x * 256 + threadIdx.x;
  if (i >= s.off[NSEG]) return;
  int sidx = 0;
#pragma unroll
  for (int k = 1; k < NSEG; k++) if (i >= s.off[k]) sidx = k;
  int j = i - s.off[sidx];
  u16 v;
  if (*flag) v = f2bf(((const float*)s.src[sidx])[j]);
  else       v = ((const u16*)s.src[sidx])[j];
  dst[i] = v;
}

// ---------------- repack kernels (embedding conv -> GEMM) ----------------
__global__ void repack_w(const u16* __restrict__ tokw, u16* __restrict__ Wg) {
  int idx = blockIdx.x * 256 + threadIdx.x;   // 512*192
  if (idx >= 512 * KEMB) return;
  int d = idx / KEMB, j = idx % KEMB, k = j >> 6, c = j & 63;
  Wg[idx] = (c < CC) ? tokw[d * (CC * 3) + c * 3 + k] : (u16)0;
}

__global__ void repack_x(const u16* __restrict__ x, u16* __restrict__ Xg) {
  int idx = blockIdx.x * 256 + threadIdx.x;   // 25600*192
  if (idx >= MM * KEMB) return;
  int m = idx / KEMB, j = idx % KEMB, k = j >> 6, c = j & 63;
  int b = m / LL, l = m % LL;
  int l2 = l + k - 1; l2 = (l2 + LL) % LL;    // circular pad
  Xg[idx] = (c < CC) ? x[(size_t)(b * LL + l2) * CC + c] : (u16)0;
}

// ---------------- bf16 MFMA GEMM: out = A[M,K] @ W[N,K]^T (+epilogue) ----------------
// R0 2-phase structure: used for emb (short K under-amortizes the counted-vmcnt
// prologue -- R13 measured null) and proj (N=55 direct-store tail).
struct GemmW { const u16* W[3]; const u16* bias[3]; void* out[3]; };

template<int BM, int BN, int NTT, int TAG, bool QKV, bool DIRECT>
__global__ __launch_bounds__(256)
void gemm_bt(const u16* __restrict__ A, int K, GemmW w,
             const u16* __restrict__ pe,
             const u16* __restrict__ resid,
             int dogelu,
             int ldo, int nvalid,
             const int* __restrict__ dtf)    // DIRECT only: *dtf==1 -> fp32 store
{
  constexpr int BK = 32;
  constexpr int MI = BM / 32;
  constexpr int CW = BN / 2, NT = CW / 16;
  constexpr int SW = CW + 4;
  constexpr int STAGE_U16 = (BM + BN) * BK * 2;
  __shared__ alignas(16) u16 smem[STAGE_U16];
  u16* As = smem;
  u16* Bs = smem + BM * BK * 2;

  const int tid = threadIdx.x;
  const int lane = tid & 63;
  const int wv = __builtin_amdgcn_readfirstlane(tid >> 6);
  const int wm = wv & 1, wn = wv >> 1;
  const int l15 = lane & 15, qd = lane >> 4;
  const int swz = swz_row(l15);

  const int id = blockIdx.x;
  const int mpx = gridDim.x / (NTT * 8);
  const int xcd = id & 7, slot = id >> 3;
  const int m_t = xcd * mpx + slot / NTT;
  const int n_t = slot % NTT;
  const int m0 = m_t * BM;
  int n0 = n_t * BN;
  int sel = 0, n0l = n0;
  if (QKV) { sel = n0 >> 9; n0l = n0 & 511; }
  const u16* W = w.W[sel];
  const u16* bias = w.bias[sel];
  void* outp = w.out[sel];

  const f32x4 zf = {0.f, 0.f, 0.f, 0.f};
  f32x4 acc[MI][NT];
#pragma unroll
  for (int i = 0; i < MI; i++)
#pragma unroll
    for (int j = 0; j < NT; j++) acc[i][j] = zf;

  for (int k0 = 0; k0 < K; k0 += 2 * BK) {
    __syncthreads();
#pragma unroll
    for (int p = 0; p < 2; p++) {
      u16* Asp = As + p * BM * BK;
      u16* Bsp = Bs + p * BN * BK;
      const int kp = k0 + p * BK;
#pragma unroll
      for (int i = 0; i < BM / 64; i++) {
        int base = i * 256 + wv * 64;
        int idx = base + lane;
        int row = idx >> 2;
        int cs = ((idx & 3) ^ swz_row(row)) * 8;
        async_lds16(A + (size_t)(m0 + row) * K + kp + cs, Asp + base * 8);
      }
#pragma unroll
      for (int i = 0; i < BN / 64; i++) {
        int base = i * 256 + wv * 64;
        int idx = base + lane;
        int row = idx >> 2;
        int cs = ((idx & 3) ^ swz_row(row)) * 8;
        int gr = n0l + row; if (gr >= nvalid) gr = nvalid - 1;
        async_lds16(W + (size_t)gr * K + kp + cs, Bsp + base * 8);
      }
    }
    __syncthreads();

#pragma unroll
    for (int p = 0; p < 2; p++) {
      const u16* Asp = As + p * BM * BK;
      const u16* Bsp = Bs + p * BN * BK;
      short8 af[MI], bfr[NT];
#pragma unroll
      for (int mi = 0; mi < MI; mi++)
        af[mi] = *(const short8*)&Asp[(wm * (BM / 2) + mi * 16 + l15) * BK + ((qd ^ swz) * 8)];
#pragma unroll
      for (int ni = 0; ni < NT; ni++)
        bfr[ni] = *(const short8*)&Bsp[(wn * CW + ni * 16 + l15) * BK + ((qd ^ swz) * 8)];
#pragma unroll
      for (int mi = 0; mi < MI; mi++)
#pragma unroll
        for (int ni = 0; ni < NT; ni++)
          acc[mi][ni] = __builtin_amdgcn_mfma_f32_16x16x32_bf16(af[mi], bfr[ni], acc[mi][ni], 0, 0, 0);
    }
  }

  // C/D layout: col=lane&15, row=(lane>>4)*4+reg [verified m89/m91]
  if (DIRECT) {
    const int sf = (dtf != nullptr) ? *dtf : 0;
#pragma unroll
    for (int mi = 0; mi < MI; mi++)
#pragma unroll
      for (int ni = 0; ni < NT; ni++) {
        int gcol = n0l + wn * CW + ni * 16 + l15;
        float bv = (bias && gcol < nvalid) ? bf2f(bias[gcol]) : 0.f;
#pragma unroll
        for (int r = 0; r < 4; r++) {
          int grow = m0 + wm * (BM / 2) + mi * 16 + qd * 4 + r;
          if (gcol < nvalid) {
            float v = acc[mi][ni][r] + bv;
            if (sf) ((float*)outp)[(size_t)grow * ldo + gcol] = v;
            else    ((u16*)outp)[(size_t)grow * ldo + gcol] = f2bf(v);
          }
        }
      }
    return;
  }

  __syncthreads();
  u16* slab = smem + wv * 16 * SW;
#pragma unroll
  for (int mi = 0; mi < MI; mi++) {
    const int lr = wm * (BM / 2) + mi * 16 + qd * 4;
    float v[NT][4];
    if (!QKV && resid) {
#pragma unroll
      for (int ni = 0; ni < NT; ni++) {
        int col = n0l + wn * CW + ni * 16 + l15;
#pragma unroll
        for (int r = 0; r < 4; r++)
          v[ni][r] = bf2f(resid[(size_t)(m0 + lr + r) * DD + col]);
      }
    } else {
#pragma unroll
      for (int ni = 0; ni < NT; ni++)
#pragma unroll
        for (int r = 0; r < 4; r++) v[ni][r] = 0.f;
    }
#pragma unroll
    for (int ni = 0; ni < NT; ni++) {
      const int lc = wn * CW + ni * 16 + l15;
      float bv = bias ? bf2f(bias[n0l + lc]) : 0.f;
#pragma unroll
      for (int r = 0; r < 4; r++) {
        float x = v[ni][r] + acc[mi][ni][r] + bv;
        if (!QKV && pe) x += bf2f(pe[((m0 + lr + r) % LL) * DD + n0l + lc]);
        if (!QKV && dogelu) x = 0.5f * x * (1.f + erff(x * 0.70710678118654752f));
        v[ni][r] = x;
      }
    }
#pragma unroll
    for (int ni = 0; ni < NT; ni++)
#pragma unroll
      for (int r = 0; r < 4; r++)
        slab[(qd * 4 + r) * SW + ni * 16 + l15] = f2bf(v[ni][r]);
    wave_lds_fence();
    if (BN == 128) {
      int r2 = lane >> 2, c2 = (lane & 3) * 16;
      int grow = m0 + wm * (BM / 2) + mi * 16 + r2;
      u16* op = (u16*)outp + (size_t)grow * ldo + n0l + wn * CW + c2;
      *(short8*)&op[0] = *(const short8*)&slab[r2 * SW + c2];
      *(short8*)&op[8] = *(const short8*)&slab[r2 * SW + c2 + 8];
    } else {
      if (lane < 32) {
        int r2 = lane >> 1, c2 = (lane & 1) * 16;
        int grow = m0 + wm * (BM / 2) + mi * 16 + r2;
        u16* op = (u16*)outp + (size_t)grow * ldo + n0l + wn * CW + c2;
        *(short8*)&op[0] = *(const short8*)&slab[r2 * SW + c2];
        *(short8*)&op[8] = *(const short8*)&slab[r2 * SW + c2 + 8];
      }
    }
    wave_lds_fence();
  }
}

// ---------------- QKV GEMM: counted-vmcnt 3-slot ring, 512 threads ----------------
// VERBATIM from the verified R8 build (52.6us, MfmaUtil 30, 2 blk/CU).
__global__ __launch_bounds__(512)
void gemm_qkv(const u16* __restrict__ A, GemmW w)
{
  constexpr int K = DD;              // 512
  constexpr int NBK = K >> 5;        // 16
  constexpr int SLOT = 12288;        // u16/slot: A 128*32 + B 256*32
  __shared__ alignas(16) u16 smem[3 * SLOT];   // 72 KB

  const int tid = threadIdx.x;
  const int lane = tid & 63;
  const int wv = __builtin_amdgcn_readfirstlane(tid >> 6);   // 0..7
  const int wm = wv & 1, wn = wv >> 1;                       // 2 x 4
  const int l15 = lane & 15, qd = lane >> 4;
  const int swk = ((qd ^ swz_row(l15)) & 3) * 8;

  const int id = blockIdx.x;
  const int mpx = gridDim.x / 48;    // 25 (grid 1200 = 8 xcd * 25 m * 6 n)
  const int xcd = id & 7, sl = id >> 3;
  const int m_t = xcd * mpx + sl / 6;
  const int n_t = sl % 6;
  const int m0 = m_t * 128;
  const int sel = n_t >> 1;
  const int n0l = (n_t & 1) * 256;
  const u16* W = w.W[sel];
  const u16* bias = w.bias[sel];
  u16* outp = (u16*)w.out[sel];

  // per-thread staging sources (3 x 16B per K-step: 1 A-chunk, 2 B-chunks)
  const int arow = tid >> 2;
  const u16* a_src = A + (size_t)(m0 + arow) * K + ((tid & 3) ^ swz_row(arow)) * 8;
  const int br0 = tid >> 2, br1 = 128 + (tid >> 2);
  const u16* b_src0 = W + (size_t)(n0l + br0) * K + ((tid & 3) ^ swz_row(br0)) * 8;
  const u16* b_src1 = W + (size_t)(n0l + br1) * K + ((tid & 3) ^ swz_row(br1)) * 8;
  const int a_dst  = wv * 512;            // uniform; HW adds lane*16B
  const int b_dst0 = 4096 + wv * 512;
  const int b_dst1 = 8192 + wv * 512;

  auto STAGE = [&](int t) {
    u16* sb = smem + (t % 3) * SLOT;
    const int kp = t << 5;
    async_lds16(a_src + kp,  sb + a_dst);
    async_lds16(b_src0 + kp, sb + b_dst0);
    async_lds16(b_src1 + kp, sb + b_dst1);
  };

  const f32x4 zf = {0.f, 0.f, 0.f, 0.f};
  f32x4 acc[4][4];
#pragma unroll
  for (int i = 0; i < 4; i++)
#pragma unroll
    for (int j = 0; j < 4; j++) acc[i][j] = zf;

  STAGE(0);
  STAGE(1);
  for (int s = 0; s < NBK; ++s) {
    if (s + 1 < NBK) {
      asm volatile("s_waitcnt vmcnt(3)" ::: "memory");   // stage(s) landed
    } else {
      asm volatile("s_waitcnt vmcnt(0)" ::: "memory");
    }
    __builtin_amdgcn_s_barrier();                        // raw: no drain
    asm volatile("" ::: "memory");
    if (s + 2 < NBK) STAGE(s + 2);                       // post-barrier: slot safe
    const u16* sb = smem + (s % 3) * SLOT;
    short8 af[4], bf[4];
#pragma unroll
    for (int mi = 0; mi < 4; mi++)
      af[mi] = *(const short8*)&sb[(wm * 64 + mi * 16 + l15) * 32 + swk];
#pragma unroll
    for (int ni = 0; ni < 4; ni++)
      bf[ni] = *(const short8*)&sb[4096 + (wn * 64 + ni * 16 + l15) * 32 + swk];
#pragma unroll
    for (int mi = 0; mi < 4; mi++)
#pragma unroll
      for (int ni = 0; ni < 4; ni++)
        acc[mi][ni] = __builtin_amdgcn_mfma_f32_16x16x32_bf16(af[mi], bf[ni], acc[mi][ni], 0, 0, 0);
    asm volatile("s_waitcnt lgkmcnt(0)" ::: "memory");   // my reads done pre-next-barrier
  }
  __syncthreads();   // all landed (vmcnt(0) at s=NBK-1); LDS reused as slab

  // epilogue: per-wave private 64x72 slab -> coalesced 16B stores
  u16* slab = smem + wv * 4608;   // 8 waves x 9 KB = 72 KB: exact fit
#pragma unroll
  for (int mi = 0; mi < 4; mi++)
#pragma unroll
    for (int ni = 0; ni < 4; ni++) {
      float bv = bf2f(bias[n0l + wn * 64 + ni * 16 + l15]);
#pragma unroll
      for (int r = 0; r < 4; r++)
        slab[(mi * 16 + qd * 4 + r) * 72 + ni * 16 + l15] = f2bf(acc[mi][ni][r] + bv);
    }
  wave_lds_fence();
  {
    const int srow = lane >> 3, chk = lane & 7;
#pragma unroll
    for (int j = 0; j < 8; j++) {
      int row = j * 8 + srow;
      int grow = m0 + wm * 64 + row;
      u16* op = outp + (size_t)grow * DD + n0l + wn * 64 + chk * 8;
      *(short8*)op = *(const short8*)&slab[row * 72 + chk * 8];
    }
  }
}

// ---------------- Wo GEMM: counted-vmcnt 3-slot ring, BN=128, grid 800 ----------------
// R23 (validated R12: total 599.8->568.1). LDS 48KB -> 3 blk/CU; grid 800 fills
// one full round of 768 slots. 2 loads/thread/stage -> vmcnt(2). Resid epilogue
// in-place safe (wave reads only its own disjoint output tile before storing).
__global__ __launch_bounds__(512)
void gemm_wo(const u16* __restrict__ A, const u16* __restrict__ W,
             const u16* __restrict__ bias, const u16* __restrict__ resid,
             u16* __restrict__ outp)
{
  constexpr int K = DD;              // 512
  constexpr int NBK = K >> 5;        // 16
  constexpr int SLOT = 8192;         // u16/slot: A 128*32 + B 128*32
  __shared__ alignas(16) u16 smem[3 * SLOT];   // 48 KB

  const int tid = threadIdx.x;
  const int lane = tid & 63;
  const int wv = __builtin_amdgcn_readfirstlane(tid >> 6);
  const int wm = wv & 1, wn = wv >> 1;         // 2M x 4N
  const int l15 = lane & 15, qd = lane >> 4;
  const int swk = ((qd ^ swz_row(l15)) & 3) * 8;

  const int id = blockIdx.x;
  const int mpx = gridDim.x >> 5;    // 25 (grid 800 = 8 xcd * 25 m * 4 n)
  const int xcd = id & 7, sl = id >> 3;
  const int m_t = xcd * mpx + (sl >> 2);
  const int m0 = m_t * 128;
  const int n0l = (sl & 3) * 128;

  const int prow = tid >> 2;         // 0..127
  const int pcs = ((tid & 3) ^ swz_row(prow)) * 8;
  const u16* a_src = A + (size_t)(m0 + prow) * K + pcs;
  const u16* b_src = W + (size_t)(n0l + prow) * K + pcs;
  const int a_dst = wv * 512;
  const int b_dst = 4096 + wv * 512;

  auto STAGE = [&](int t) {
    u16* sb = smem + (t % 3) * SLOT;
    const int kp = t << 5;
    async_lds16(a_src + kp, sb + a_dst);
    async_lds16(b_src + kp, sb + b_dst);
  };

  const f32x4 zf = {0.f, 0.f, 0.f, 0.f};
  f32x4 acc[4][2];
#pragma unroll
  for (int i = 0; i < 4; i++)
#pragma unroll
    for (int j = 0; j < 2; j++) acc[i][j] = zf;

  STAGE(0);
  STAGE(1);
  for (int s = 0; s < NBK; ++s) {
    if (s + 1 < NBK) {
      asm volatile("s_waitcnt vmcnt(2)" ::: "memory");   // stage(s) landed
    } else {
      asm volatile("s_waitcnt vmcnt(0)" ::: "memory");
    }
    __builtin_amdgcn_s_barrier();                        // raw: no drain
    asm volatile("" ::: "memory");
    if (s + 2 < NBK) STAGE(s + 2);                       // post-barrier: slot safe
    const u16* sb = smem + (s % 3) * SLOT;
    short8 af[4], bf[2];
#pragma unroll
    for (int mi = 0; mi < 4; mi++)
      af[mi] = *(const short8*)&sb[(wm * 64 + mi * 16 + l15) * 32 + swk];
#pragma unroll
    for (int ni = 0; ni < 2; ni++)
      bf[ni] = *(const short8*)&sb[4096 + (wn * 32 + ni * 16 + l15) * 32 + swk];
#pragma unroll
    for (int mi = 0; mi < 4; mi++)
#pragma unroll
      for (int ni = 0; ni < 2; ni++)
        acc[mi][ni] = __builtin_amdgcn_mfma_f32_16x16x32_bf16(af[mi], bf[ni], acc[mi][ni], 0, 0, 0);
    asm volatile("s_waitcnt lgkmcnt(0)" ::: "memory");   // my reads done pre-next-barrier
  }
  __syncthreads();   // all landed; LDS reused as slab

  // epilogue: per-wave private 64x36 slab -> coalesced 16B stores
  u16* slab = smem + wv * 2304;   // 8 waves x 4.5 KB = 36 KB <= 48 KB
#pragma unroll
  for (int mi = 0; mi < 4; mi++)
#pragma unroll
    for (int ni = 0; ni < 2; ni++) {
      const int col = n0l + wn * 32 + ni * 16 + l15;
      float bv = bf2f(bias[col]);
#pragma unroll
      for (int r = 0; r < 4; r++) {
        const int grow = m0 + wm * 64 + mi * 16 + qd * 4 + r;
        float x = acc[mi][ni][r] + bv + bf2f(resid[(size_t)grow * DD + col]);
        slab[(mi * 16 + qd * 4 + r) * 36 + ni * 16 + l15] = f2bf(x);
      }
    }
  wave_lds_fence();
  {
    const int srow = lane >> 2, chk = lane & 3;   // 16 rows x 4 chunks per pass
#pragma unroll
    for (int j = 0; j < 4; j++) {
      int row = j * 16 + srow;
      int grow = m0 + wm * 64 + row;
      u16* op = outp + (size_t)grow * DD + n0l + wn * 32 + chk * 8;
      *(short8*)op = *(const short8*)&slab[row * 36 + chk * 8];
    }
  }
}

// ---------------- fused FFN: hout = h + gelu(h@W1^T + b1) @ W2^T + b2 ----------------
// R25: phase 1 (K=512 -> NBK=16, qualifies per validated rule) ported to the
// proven 3-slot counted-vmcnt ring (gemm_wo structure, 256-thread variant):
// one raw barrier/step, vmcnt(2) counted, never 0 until the peeled last step.
// Phase 2 (K=64: too short per R13) unchanged. N-split grid 800, ping-pong out.
__global__ __launch_bounds__(256)
void ffn_fused(const u16* __restrict__ h, const u16* __restrict__ W1,
               const u16* __restrict__ b1, const u16* __restrict__ W2,
               const u16* __restrict__ b2, u16* __restrict__ hout)
{
  constexpr int BK = 32, SW = 36;
  constexpr int NBK = DD >> 5;               // 16
  constexpr int SLOT = 4096;                 // u16/slot: A 64*32 + B 64*32 (8 KB)
  __shared__ alignas(16) u16 smem[16896];    // 33 KB -> 4 blk/CU
  u16* y     = smem;                         // [2][64][32] phase-1 out (swizzled)
  u16* ring  = smem + 4096;                  // 3 slots x 4096 (phase 1)
  u16* Bs2   = smem + 4096;                  // phase 2 aliases ring (post-drain)
  u16* slabs = smem + 12288;                 // 8 waves... 4 waves x 16*36

  const int tid = threadIdx.x;
  const int lane = tid & 63;
  const int wv = __builtin_amdgcn_readfirstlane(tid >> 6);   // 0..3
  const int wm = wv & 1, wn = wv >> 1;                       // 2M x 2N
  const int l15 = lane & 15, qd = lane >> 4;
  const int swz = swz_row(l15);
  const int swk = ((qd ^ swz) & 3) * 8;
  const int id = blockIdx.x;
  const int mpx = gridDim.x >> 3;            // 100
  const int lid = (id & 7) * mpx + (id >> 3);  // XCD-contiguous 0..799
  const int m0 = (lid >> 1) * 64;
  const int nh = lid & 1;                    // phase-2 N-half

  const int prow = tid >> 2;                 // 0..63
  const int pcs = ((tid & 3) ^ swz_row(prow)) * 8;
  const u16* a_src = h  + (size_t)(m0 + prow) * DD + pcs;
  const u16* b_src = W1 + (size_t)prow * DD + pcs;
  const f32x4 zf = {0.f, 0.f, 0.f, 0.f};

  auto STAGE1 = [&](int t) {
    u16* sb = ring + (t % 3) * SLOT;
    const int kp = t << 5;
    async_lds16(a_src + kp, sb + wv * 512);
    async_lds16(b_src + kp, sb + 2048 + wv * 512);
  };

  // ---- phase 1: y = gelu(h @ W1^T + b1), counted-vmcnt 3-slot ring ----
  f32x4 acc[2][2];
#pragma unroll
  for (int i = 0; i < 2; i++)
#pragma unroll
    for (int j = 0; j < 2; j++) acc[i][j] = zf;

  STAGE1(0);
  STAGE1(1);
  for (int s = 0; s < NBK; ++s) {
    if (s + 1 < NBK) {
      asm volatile("s_waitcnt vmcnt(2)" ::: "memory");   // stage(s) landed
    } else {
      asm volatile("s_waitcnt vmcnt(0)" ::: "memory");
    }
    __builtin_amdgcn_s_barrier();                        // raw: no drain
    asm volatile("" ::: "memory");
    if (s + 2 < NBK) STAGE1(s + 2);                      // post-barrier: slot safe
    const u16* sb = ring + (s % 3) * SLOT;
    short8 af[2], bfr[2];
#pragma unroll
    for (int mi = 0; mi < 2; mi++)
      af[mi] = *(const short8*)&sb[(wm * 32 + mi * 16 + l15) * BK + swk];
#pragma unroll
    for (int ni = 0; ni < 2; ni++)
      bfr[ni] = *(const short8*)&sb[2048 + (wn * 32 + ni * 16 + l15) * BK + swk];
#pragma unroll
    for (int mi = 0; mi < 2; mi++)
#pragma unroll
      for (int ni = 0; ni < 2; ni++)
        acc[mi][ni] = __builtin_amdgcn_mfma_f32_16x16x32_bf16(af[mi], bfr[ni], acc[mi][ni], 0, 0, 0);
    asm volatile("s_waitcnt lgkmcnt(0)" ::: "memory");   // my reads done pre-next-barrier
  }
  // y park (swizzled): element (row, kpos) -> slot (kpos>>3) ^ sw(row).
  // y is disjoint from ring; each thread writes only its own acc cells.
#pragma unroll
  for (int mi = 0; mi < 2; mi++)
#pragma unroll
    for (int ni = 0; ni < 2; ni++) {
      float bv = bf2f(b1[wn * 32 + ni * 16 + l15]);
#pragma unroll
      for (int r = 0; r < 4; r++) {
        int row = wm * 32 + mi * 16 + qd * 4 + r;
        int kpos = ni * 16 + l15;
        int slot = ((kpos >> 3) ^ swz_row(row)) & 3;
        float x = acc[mi][ni][r] + bv;
        x = 0.5f * x * (1.f + erff(x * 0.70710678118654752f));
        y[wn * 2048 + row * BK + slot * 8 + (kpos & 7)] = f2bf(x);
      }
    }
  __syncthreads();   // y visible; all ring reads complete -> Bs2 may overwrite

  // ---- phase 2: hout = h + y @ W2^T + b2, 4 chunks of 64 cols (this half) ----
  auto stage2 = [&](int buf, int nc) {
#pragma unroll
    for (int p = 0; p < 2; p++)
      async_lds16(W2 + (size_t)(nc * 64 + prow) * 64 + p * BK + pcs,
                  Bs2 + buf * 4096 + p * 2048 + tid * 8);
  };
  const int nc0 = nh * 4, nc1 = nc0 + 4;
  stage2(0, nc0);
  int cur = 0;
  u16* slab = slabs + wv * 16 * SW;
  for (int nc = nc0; nc < nc1; nc++) {
    __syncthreads();
    if (nc + 1 < nc1) stage2(cur ^ 1, nc + 1);
    f32x4 a2[2][2];
#pragma unroll
    for (int i = 0; i < 2; i++)
#pragma unroll
      for (int j = 0; j < 2; j++) a2[i][j] = zf;
#pragma unroll
    for (int p = 0; p < 2; p++) {
      short8 af[2], bfr[2];
#pragma unroll
      for (int mi = 0; mi < 2; mi++)
        af[mi] = *(const short8*)&y[p * 2048 + (wm * 32 + mi * 16 + l15) * BK + ((qd ^ swz) * 8)];
#pragma unroll
      for (int ni = 0; ni < 2; ni++)
        bfr[ni] = *(const short8*)&Bs2[cur * 4096 + p * 2048 + (wn * 32 + ni * 16 + l15) * BK + ((qd ^ swz) * 8)];
#pragma unroll
      for (int mi = 0; mi < 2; mi++)
#pragma unroll
        for (int ni = 0; ni < 2; ni++)
          a2[mi][ni] = __builtin_amdgcn_mfma_f32_16x16x32_bf16(af[mi], bfr[ni], a2[mi][ni], 0, 0, 0);
    }
    const int n0l = nc * 64;
#pragma unroll
    for (int mi = 0; mi < 2; mi++) {
      const int lr = wm * 32 + mi * 16 + qd * 4;
      float v[2][4];
#pragma unroll
      for (int ni = 0; ni < 2; ni++) {
        int col = n0l + wn * 32 + ni * 16 + l15;
        float bv = bf2f(b2[col]);
#pragma unroll
        for (int r = 0; r < 4; r++)
          v[ni][r] = bf2f(h[(size_t)(m0 + lr + r) * DD + col]) + a2[mi][ni][r] + bv;
      }
#pragma unroll
      for (int ni = 0; ni < 2; ni++)
#pragma unroll
        for (int r = 0; r < 4; r++)
          slab[(qd * 4 + r) * SW + ni * 16 + l15] = f2bf(v[ni][r]);
      wave_lds_fence();
      if (lane < 32) {
        int r2 = lane >> 1, c2 = (lane & 1) * 16;
        int grow = m0 + wm * 32 + mi * 16 + r2;
        u16* op = hout + (size_t)grow * DD + n0l + wn * 32 + c2;
        *(short8*)&op[0] = *(const short8*)&slab[r2 * SW + c2];
        *(short8*)&op[8] = *(const short8*)&slab[r2 * SW + c2 + 8];
      }
      wave_lds_fence();
    }
    cur ^= 1;
  }
}

// ---------------- fused attention: one block per (b,h) ----------------
// R17: LDS 32 KB (P parked in dead Ks region, PV in two 64-col passes).
__global__ __launch_bounds__(256)
void attn(const u16* __restrict__ qg, const u16* __restrict__ kg,
          const u16* __restrict__ vg, u16* __restrict__ og)
{
  constexpr int LP = 128;
  __shared__ alignas(16) u16 Ks[LP * DKK];   // 16 KB; post-QK^T: P-chunk, then Os
  __shared__ alignas(16) u16 Vt[DKK * LP];   // 16 KB

  const int bh = blockIdx.x;
  const int b = bh >> 3, h = bh & 7;
  const size_t base = (size_t)b * LL * DD + (size_t)h * DKK;
  const int tid = threadIdx.x, lane = tid & 63, wv = tid >> 6;
  const int l15 = lane & 15, qd = lane >> 4;
  const short8 z8 = {0, 0, 0, 0, 0, 0, 0, 0};

  for (int i = tid; i < LP * 8; i += 256) {
    int row = i >> 3, e8 = (i & 7) * 8;
    short8 val = z8;
    if (row < LL) val = *(const short8*)(kg + base + (size_t)row * DD + e8);
    *(short8*)&Ks[row * DKK + e8] = val;
  }
  for (int i = tid; i < LP * 8; i += 256) {
    int j = i & 127, d0 = (i >> 7) * 8;
    short8 val = z8;
    if (j < LL) val = *(const short8*)(vg + base + (size_t)j * DD + d0);
#pragma unroll
    for (int u = 0; u < 8; u++) Vt[(d0 + u) * LP + j] = (u16)val[u];
  }
  __syncthreads();

  const f32x4 zf = {0.f, 0.f, 0.f, 0.f};
  f32x4 sc[2][8];
#pragma unroll
  for (int it = 0; it < 2; it++)
#pragma unroll
    for (int jt = 0; jt < 8; jt++) sc[it][jt] = zf;

  short8 af[2][2];
#pragma unroll
  for (int it = 0; it < 2; it++) {
    int row = (2 * wv + it) * 16 + l15;
#pragma unroll
    for (int ks = 0; ks < 2; ks++) {
      short8 val = z8;
      if (row < LL) val = *(const short8*)(qg + base + (size_t)row * DD + ks * 32 + qd * 8);
      af[it][ks] = val;
    }
  }
#pragma unroll
  for (int jt = 0; jt < 8; jt++) {
    short8 b0 = *(const short8*)&Ks[(jt * 16 + l15) * DKK + qd * 8];
    short8 b1 = *(const short8*)&Ks[(jt * 16 + l15) * DKK + 32 + qd * 8];
#pragma unroll
    for (int it = 0; it < 2; it++) {
      sc[it][jt] = __builtin_amdgcn_mfma_f32_16x16x32_bf16(af[it][0], b0, sc[it][jt], 0, 0, 0);
      sc[it][jt] = __builtin_amdgcn_mfma_f32_16x16x32_bf16(af[it][1], b1, sc[it][jt], 0, 0, 0);
    }
  }

  // softmax fully in registers: sc := P (normalized probabilities)
  constexpr float scale = 0.125f;
#pragma unroll
  for (int it = 0; it < 2; it++) {
#pragma unroll
    for (int r = 0; r < 4; r++) {
      float vals[8];
      float mx = -1e30f;
#pragma unroll
      for (int jt = 0; jt < 8; jt++) {
        int col = jt * 16 + l15;
        float vv = sc[it][jt][r] * scale;
        if (col >= LL) vv = -1e30f;
        vals[jt] = vv;
        mx = fmaxf(mx, vv);
      }
#pragma unroll
      for (int off = 1; off < 16; off <<= 1) mx = fmaxf(mx, __shfl_xor(mx, off, 64));
      float s = 0.f;
#pragma unroll
      for (int jt = 0; jt < 8; jt++) { float p = __expf(vals[jt] - mx); vals[jt] = p; s += p; }
#pragma unroll
      for (int off = 1; off < 16; off <<= 1) s += __shfl_xor(s, off, 64);
      float inv = 1.f / s;
#pragma unroll
      for (int jt = 0; jt < 8; jt++) sc[it][jt][r] = vals[jt] * inv;
    }
  }
  __syncthreads();   // all waves' QK^T reads of Ks complete -> Ks reusable

  u16* Pc = Ks;      // P-chunk [128][64]
  f32x4 oc[2][4];
#pragma unroll
  for (int it = 0; it < 2; it++)
#pragma unroll
    for (int dt = 0; dt < 4; dt++) oc[it][dt] = zf;

  // ---- pass A: P cols 0..63 -> PV k-slices 0,1 ----
#pragma unroll
  for (int it = 0; it < 2; it++) {
    int rb = (2 * wv + it) * 16 + qd * 4;
#pragma unroll
    for (int r = 0; r < 4; r++)
#pragma unroll
      for (int jt = 0; jt < 4; jt++)
        Pc[(rb + r) * DKK + jt * 16 + l15] = f2bf(sc[it][jt][r]);
  }
  __syncthreads();
#pragma unroll
  for (int ks = 0; ks < 2; ks++) {
    short8 ap[2];
#pragma unroll
    for (int it = 0; it < 2; it++)
      ap[it] = *(const short8*)&Pc[((2 * wv + it) * 16 + l15) * DKK + ks * 32 + qd * 8];
#pragma unroll
    for (int dt = 0; dt < 4; dt++) {
      short8 bv = *(const short8*)&Vt[(dt * 16 + l15) * LP + ks * 32 + qd * 8];
#pragma unroll
      for (int it = 0; it < 2; it++)
        oc[it][dt] = __builtin_amdgcn_mfma_f32_16x16x32_bf16(ap[it], bv, oc[it][dt], 0, 0, 0);
    }
  }
  __syncthreads();

  // ---- pass B: P cols 64..127 -> PV k-slices 2,3 ----
#pragma unroll
  for (int it = 0; it < 2; it++) {
    int rb = (2 * wv + it) * 16 + qd * 4;
#pragma unroll
    for (int r = 0; r < 4; r++)
#pragma unroll
      for (int jt = 4; jt < 8; jt++)
        Pc[(rb + r) * DKK + (jt - 4) * 16 + l15] = f2bf(sc[it][jt][r]);
  }
  __syncthreads();
#pragma unroll
  for (int ks = 2; ks < 4; ks++) {
    short8 ap[2];
#pragma unroll
    for (int it = 0; it < 2; it++)
      ap[it] = *(const short8*)&Pc[((2 * wv + it) * 16 + l15) * DKK + (ks - 2) * 32 + qd * 8];
#pragma unroll
    for (int dt = 0; dt < 4; dt++) {
      short8 bv = *(const short8*)&Vt[(dt * 16 + l15) * LP + ks * 32 + qd * 8];
#pragma unroll
      for (int it = 0; it < 2; it++)
        oc[it][dt] = __builtin_amdgcn_mfma_f32_16x16x32_bf16(ap[it], bv, oc[it][dt], 0, 0, 0);
    }
  }

  __syncthreads();
  u16* Os = Ks;      // [128][64], Pc dead
#pragma unroll
  for (int it = 0; it < 2; it++) {
    int rb = (2 * wv + it) * 16 + qd * 4;
#pragma unroll
    for (int dt = 0; dt < 4; dt++)
#pragma unroll
      for (int r = 0; r < 4; r++)
        Os[(rb + r) * DKK + dt * 16 + l15] = f2bf(oc[it][dt][r]);
  }
  __syncthreads();
  {
    int row = tid >> 1, c0 = (tid & 1) * 32;
    if (row < LL) {
      u16* op = og + base + (size_t)row * DD + c0;
#pragma unroll
      for (int c = 0; c < 32; c += 8)
        *(short8*)&op[c] = *(const short8*)&Os[row * DKK + c0 + c];
    }
  }
}

// ---------------- launch ----------------
extern "C" void kernel_launch(void* const* d_in, const int* in_sizes, int n_in,
                              void* d_out, int out_size, void* d_ws, size_t ws_size,
                              hipStream_t stream)
{
  (void)in_sizes; (void)n_in; (void)out_size; (void)ws_size;

  char* ws = (char*)d_ws;
  size_t off = 0;
  auto alloc = [&](size_t bytes) { char* p = ws + off; off += (bytes + 255) & ~(size_t)255; return p; };
  int* dflag = (int*)alloc(256);
  static const int seg_sizes[NSEG] = {
    MM * CC, DD * CC * 3, LL * DD,
    3 * DD * DD, 3 * DD, 3 * DD * DD, 3 * DD, 3 * DD * DD, 3 * DD,
    3 * DD * DD, 3 * DD, 3 * 64 * DD, 3 * 64, 3 * DD * 64, 3 * DD,
    CC * DD, CC
  };
  static const int seg_input[NSEG] = {0, 1, 2, 3, 4, 5, 6, 7, 8, 11, 12, 13, 14, 15, 16, 17, 18};
  int total = 0, segoff[NSEG + 1];
  for (int i = 0; i < NSEG; i++) { segoff[i] = total; total += seg_sizes[i]; }
  segoff[NSEG] = total;
  u16* canon = (u16*)alloc((size_t)total * 2);

  u16* hbf = (u16*)alloc((size_t)MM * DD * 2);   // residual stream (ping)
  u16* h2  = (u16*)alloc((size_t)MM * DD * 2);   // residual stream (pong, FFN out)
  u16* qb  = (u16*)alloc((size_t)MM * DD * 2);
  u16* kb  = (u16*)alloc((size_t)MM * DD * 2);
  u16* vb  = (u16*)alloc((size_t)MM * DD * 2);
  u16* ob  = (u16*)alloc((size_t)MM * DD * 2);
  u16* Wg  = (u16*)alloc((size_t)512 * KEMB * 2);
  u16* Xg  = qb;   // alias: Xg dead before qb first written (stream-serialized)

  const u16* xc  = canon + segoff[0];
  const u16* twc = canon + segoff[1];
  const u16* pec = canon + segoff[2];
  const u16* Wqc = canon + segoff[3];  const u16* bqc = canon + segoff[4];
  const u16* Wkc = canon + segoff[5];  const u16* bkc = canon + segoff[6];
  const u16* Wvc = canon + segoff[7];  const u16* bvc = canon + segoff[8];
  const u16* Woc = canon + segoff[9];  const u16* boc = canon + segoff[10];
  const u16* W1c = canon + segoff[11]; const u16* b1c = canon + segoff[12];
  const u16* W2c = canon + segoff[13]; const u16* b2c = canon + segoff[14];
  const u16* pwc = canon + segoff[15]; const u16* pbc = canon + segoff[16];

  Segs sg;
  for (int i = 0; i < NSEG; i++) { sg.src[i] = d_in[seg_input[i]]; sg.off[i] = segoff[i]; }
  sg.off[NSEG] = total;

  dim3 blk(256);
  detect_dtype<<<dim3(1), blk, 0, stream>>>((const u16*)d_in[0], dflag);
  convert_all<<<dim3((total + 255) / 256), blk, 0, stream>>>(sg, dflag, canon);
  repack_w<<<dim3((512 * KEMB + 255) / 256), blk, 0, stream>>>(twc, Wg);
  repack_x<<<dim3((MM * KEMB + 255) / 256), blk, 0, stream>>>(xc, Xg);

  auto W1of = [&](const u16* p) { GemmW g{}; g.W[0] = g.W[1] = g.W[2] = p; return g; };

  // embedding GEMM: h = Xg @ Wg^T + pe -> hbf   [TAG 0]  grid 200*8, XCD-decoded
  { GemmW g = W1of(Wg); g.out[0] = hbf;
    gemm_bt<128, 64, 8, 0, false, false><<<dim3(1600), blk, 0, stream>>>(Xg, KEMB, g, pec, nullptr, 0, DD, DD, nullptr); }

  u16* hc = hbf;   // current residual stream
  for (int l = 0; l < 3; l++) {
    const u16* Wq_l = Wqc + (size_t)l * DD * DD; const u16* bq_l = bqc + l * DD;
    const u16* Wk_l = Wkc + (size_t)l * DD * DD; const u16* bk_l = bkc + l * DD;
    const u16* Wv_l = Wvc + (size_t)l * DD * DD; const u16* bv_l = bvc + l * DD;
    const u16* Wo_l = Woc + (size_t)l * DD * DD; const u16* bo_l = boc + l * DD;
    const u16* W1_l = W1c + (size_t)l * 64 * DD; const u16* b1_l = b1c + l * 64;
    const u16* W2_l = W2c + (size_t)l * DD * 64; const u16* b2_l = b2c + l * DD;

    // fused QKV: counted-vmcnt 3-slot pipeline, grid 8*25*6 = 1200, 512 threads
    { GemmW g{}; g.W[0] = Wq_l; g.W[1] = Wk_l; g.W[2] = Wv_l;
      g.bias[0] = bq_l; g.bias[1] = bk_l; g.bias[2] = bv_l;
      g.out[0] = qb; g.out[1] = kb; g.out[2] = vb;
      gemm_qkv<<<dim3(1200), dim3(512), 0, stream>>>(hc, g); }

    attn<<<dim3(BB * HH), blk, 0, stream>>>(qb, kb, vb, ob);

    // h = h + o @ Wo^T + bo  (counted-vmcnt BN=128 grid 800, resid epilogue, in-place)
    gemm_wo<<<dim3(800), dim3(512), 0, stream>>>(ob, Wo_l, bo_l, hc, hc);

    // fused FFN: hn = hc + gelu(hc@W1^T+b1)@W2^T + b2  (ping-pong, N-split grid 800)
    u16* hn = (hc == hbf) ? h2 : hbf;
    ffn_fused<<<dim3(800), blk, 0, stream>>>(hc, W1_l, b1_l, W2_l, b2_l, hn);
    hc = hn;
  }
  // out = h @ proj_w^T + proj_b (N=55, direct masked stores; dtype per flag)   [TAG 5]
  { GemmW g = W1of(pwc); g.bias[0] = pbc; g.out[0] = d_out;
    gemm_bt<64, 64, 1, 5, false, true><<<dim3(400), blk, 0, stream>>>(hc, DD, g, nullptr, nullptr, 0, CC, CC, dflag); }
}